// Round 10
// baseline (181.776 us; speedup 1.0000x reference)
//
#include <hip/hip_runtime.h>

#define DIMB 2
#define DIMS 192
#define DPT 4          // d-outputs per thread
#define TX 16          // d-quads per block (64 d per block)
#define TY 16          // w rows per block
#define HCHUNK 6       // output h rows per block
#define ROWF 72        // floats per staged row (d0b-4 .. d0b+67)
#define ARR_F 432      // 6 rows * 72 floats per array in a wave slab
#define SLAB_F 1024    // floats per wave per ring slot (864 used + pad)

// Async global->LDS staging: wave-uniform LDS base + lane*16 (m104 contract);
// global source address is per-lane.
#define GLOAD_LDS16(gp, lp) __builtin_amdgcn_global_load_lds( \
    (const __attribute__((address_space(1))) void*)(gp),      \
    (__attribute__((address_space(3))) void*)(lp), 16, 0, 0)

// Counted waits (T4 idiom): keep the younger stage's loads in flight across
// the wait. "memory" clobber pins memory-op order on both sides.
#define WAITV(n) asm volatile("s_waitcnt vmcnt(" #n ")" ::: "memory")
#define LGKM0    asm volatile("s_waitcnt lgkmcnt(0)" ::: "memory")

// DPP lane shifts within 16-lane rows (tx groups): pure VALU, no LDS pipe.
__device__ __forceinline__ float dpp_left(float x) {   // value of tx-1 neighbor
    const int i = __float_as_int(x);
    return __int_as_float(__builtin_amdgcn_update_dpp(i, i, 0x111, 0xf, 0xf, false));
}
__device__ __forceinline__ float dpp_right(float x) {  // value of tx+1 neighbor
    const int i = __float_as_int(x);
    return __int_as_float(__builtin_amdgcn_update_dpp(i, i, 0x101, 0xf, 0xf, false));
}

__device__ __forceinline__ float ncc_row3(const float (&Pm)[5][DPT],
                                          const float (&Pc)[5][DPT],
                                          const float (&Pn)[5][DPT])
{
    const float inv = 1.0f / 27.0f;
    float acc = 0.f;
#pragma unroll
    for (int j = 0; j < DPT; ++j) {
        const float sI  = Pm[0][j] + Pc[0][j] + Pn[0][j];
        const float sJ  = Pm[1][j] + Pc[1][j] + Pn[1][j];
        const float sII = Pm[2][j] + Pc[2][j] + Pn[2][j];
        const float sJJ = Pm[3][j] + Pc[3][j] + Pn[3][j];
        const float sIJ = Pm[4][j] + Pc[4][j] + Pn[4][j];
        const float uI = sI * inv;
        const float uJ = sJ * inv;
        const float cross = sIJ - uI * sJ;
        const float pvar  = sII - uI * sI;
        const float tvar  = sJJ - uJ * sJ;
        acc += (cross * cross) * __builtin_amdgcn_rcpf(tvar * pvar + 1e-5f);
    }
    return acc;
}

// Window-3 d-sums with shared pair sums (compiler can't FP-reassociate).
#define WSUM(dst, a)                                            \
    { const float c12 = a[1] + a[2], c34 = a[3] + a[4];         \
      dst[0] += a[0] + c12; dst[1] += c12 + a[3];               \
      dst[2] += a[2] + c34; dst[3] += c34 + a[5]; }

// One staged row -> 5-channel window sums. Expansion-site scope provides
// tx, lo_mask, hi_mask, Lp, Lt, P.
#define ROWBODY(pm, tm, rbi)                                             \
    {                                                                    \
        float p0 = dpp_left (pm.w);                                      \
        float p5 = dpp_right(pm.x);                                      \
        float t0 = dpp_left (tm.w);                                      \
        float t5 = dpp_right(tm.x);                                      \
        if (tx == 0)      { p0 = Lp[(rbi) + 3]; t0 = Lt[(rbi) + 3]; }    \
        if (tx == TX - 1) { p5 = Lp[(rbi) + 8]; t5 = Lt[(rbi) + 8]; }    \
        if (lo_mask) { p0 = 0.f; t0 = 0.f; }                             \
        if (hi_mask) { p5 = 0.f; t5 = 0.f; }                             \
        const float pv[6] = {p0, pm.x, pm.y, pm.z, pm.w, p5};            \
        const float tv[6] = {t0, tm.x, tm.y, tm.z, tm.w, t5};            \
        float pp[6], tt[6], pt[6];                                       \
        _Pragma("unroll")                                                \
        for (int k = 0; k < 6; ++k) {                                    \
            pp[k] = pv[k] * pv[k];                                       \
            tt[k] = tv[k] * tv[k];                                       \
            pt[k] = pv[k] * tv[k];                                       \
        }                                                                \
        WSUM(P[0], pv)                                                   \
        WSUM(P[1], tv)                                                   \
        WSUM(P[2], pp)                                                   \
        WSUM(P[3], tt)                                                   \
        WSUM(P[4], pt)                                                   \
    }

__global__ __launch_bounds__(256)
void FusedLocalNormalizedCrossCorrelationLoss_37838661877790_kernel(
    const float* __restrict__ pred, const float* __restrict__ targ,
    double* __restrict__ acc_out)
{
    // Wave-private slabs, 2-slot ring (r4 structure, 65.4 us baseline).
    __shared__ float L[4][2][SLAB_F];    // 32 KB

    const int tx = threadIdx.x, ty = threadIdx.y;
    const int tid = ty * TX + tx;
    const int lane = tid & 63, wv = tid >> 6;
    const int tyw = ty & 3;                      // ty = 4*wv + tyw
    const int d0b = blockIdx.x * (TX * DPT);     // 0, 64, 128
    const int w0  = blockIdx.y * TY;
    const int bz  = blockIdx.z;
    const int b   = bz >> 5;                     // 2 batches
    const int h0  = (bz & 31) * HCHUNK;          // 32 h-chunks

    // ---- per-thread stage precompute (plane-invariant): 4 chunks/wave ----
    int co[4]; const float* ab[4];
#pragma unroll
    for (int c = 0; c < 4; ++c) {
        const int fi = c * 256 + lane * 4;
        const int a  = (fi >= ARR_F) ? 1 : 0;
        int fi2 = fi - a * ARR_F;
        if (fi2 > ARR_F - 4) fi2 = ARR_F - 4;    // pad tail -> safe duplicate
        const int r = fi2 / ROWF, cl = fi2 % ROWF;
        int gd = d0b - 4 + cl;                   // multiple of 4 -> 16B aligned
        gd = gd < 0 ? 0 : (gd > DIMS - 4 ? DIMS - 4 : gd);
        int wr = w0 - 1 + 4 * wv + r;
        wr = wr < 0 ? 0 : (wr > DIMS - 1 ? DIMS - 1 : wr);
        co[c] = wr * DIMS + gd;                  // clamped; garbage masked later
        ab[c] = a ? targ : pred;
    }

    auto stage = [&](int slot, int hh) {
        const int hhc = hh < 0 ? 0 : (hh > DIMS - 1 ? DIMS - 1 : hh);
        const size_t po = ((size_t)b * DIMS + hhc) * (DIMS * DIMS);
        float* lb = &L[wv][slot][0];             // wave-uniform base
#pragma unroll
        for (int c = 0; c < 4; ++c)
            GLOAD_LDS16(ab[c] + po + co[c], lb + c * 256);
    };

    // d-edge masks (x-direction, orthogonal to the y interior/edge split).
    const bool lo_mask = (tx == 0)      && (blockIdx.x == 0);
    const bool hi_mask = (tx == TX - 1) && (blockIdx.x == gridDim.x - 1);
    const int rb0 = 4 * tx;

    // INTERIOR plane: all 3 rows valid -> hoist all 6 ds_read_b128 into
    // locals FIRST (one batched latency exposure), then straight-line rows.
    auto planeI = [&](int slot, int hh, float (&P)[5][DPT]) {
#pragma unroll
        for (int c5 = 0; c5 < 5; ++c5)
#pragma unroll
            for (int j = 0; j < DPT; ++j) P[c5][j] = 0.f;
        if (hh < 0 || hh >= DIMS) return;        // uniform per block
        const float* Lp = &L[wv][slot][0];
        const float* Lt = Lp + ARR_F;
        const int rb = tyw * ROWF + rb0;
        const float4 pm0 = *reinterpret_cast<const float4*>(Lp + rb + 4);
        const float4 tm0 = *reinterpret_cast<const float4*>(Lt + rb + 4);
        const float4 pm1 = *reinterpret_cast<const float4*>(Lp + rb + ROWF + 4);
        const float4 tm1 = *reinterpret_cast<const float4*>(Lt + rb + ROWF + 4);
        const float4 pm2 = *reinterpret_cast<const float4*>(Lp + rb + 2 * ROWF + 4);
        const float4 tm2 = *reinterpret_cast<const float4*>(Lt + rb + 2 * ROWF + 4);
        ROWBODY(pm0, tm0, rb)
        ROWBODY(pm1, tm1, rb + ROWF)
        ROWBODY(pm2, tm2, rb + 2 * ROWF)
    };

    // EDGE plane (blockIdx.y 0 / last): r4's guarded per-row loop.
    auto planeE = [&](int slot, int hh, float (&P)[5][DPT]) {
#pragma unroll
        for (int c5 = 0; c5 < 5; ++c5)
#pragma unroll
            for (int j = 0; j < DPT; ++j) P[c5][j] = 0.f;
        if (hh < 0 || hh >= DIMS) return;
        const float* Lp = &L[wv][slot][0];
        const float* Lt = Lp + ARR_F;
#pragma unroll
        for (int dw = 0; dw < 3; ++dw) {
            const int wr = w0 + ty + dw - 1;
            if (wr < 0 || wr >= DIMS) continue;  // garbage halo row (per-ty uniform)
            const int rbi = (tyw + dw) * ROWF + rb0;
            const float4 pm = *reinterpret_cast<const float4*>(Lp + rbi + 4);
            const float4 tm = *reinterpret_cast<const float4*>(Lt + rbi + 4);
            ROWBODY(pm, tm, rbi)
        }
    };

    // Barrier-free per-wave pipeline (r4 schedule, unchanged).
    float PA[5][DPT], PB[5][DPT], PC[5][DPT];
    float acc = 0.f;

#define PIPELINE(PLANE)                                                  \
    stage(0, h0 - 1);                                                    \
    stage(1, h0);                                                        \
    WAITV(4); PLANE(0, h0 - 1, PA); LGKM0; stage(0, h0 + 1);             \
    WAITV(4); PLANE(1, h0,     PB); LGKM0; stage(1, h0 + 2);             \
    WAITV(4); PLANE(0, h0 + 1, PC); LGKM0; stage(0, h0 + 3);             \
    acc += ncc_row3(PA, PB, PC);                                         \
    WAITV(4); PLANE(1, h0 + 2, PA); LGKM0; stage(1, h0 + 4);             \
    acc += ncc_row3(PB, PC, PA);                                         \
    WAITV(4); PLANE(0, h0 + 3, PB); LGKM0; stage(0, h0 + 5);             \
    acc += ncc_row3(PC, PA, PB);                                         \
    WAITV(4); PLANE(1, h0 + 4, PC); LGKM0; stage(1, h0 + 6);             \
    acc += ncc_row3(PA, PB, PC);                                         \
    WAITV(4); PLANE(0, h0 + 5, PA);                                      \
    acc += ncc_row3(PB, PC, PA);                                         \
    WAITV(0); PLANE(1, h0 + 6, PB);                                      \
    acc += ncc_row3(PC, PA, PB);

    const bool interior = (blockIdx.y != 0) && (blockIdx.y != gridDim.y - 1);
    if (interior) {
        PIPELINE(planeI)
    } else {
        PIPELINE(planeE)
    }
#undef PIPELINE

    // Reduction: wave shuffle tree -> LDS -> one fp64 atomic per block.
#pragma unroll
    for (int off = 32; off > 0; off >>= 1)
        acc += __shfl_down(acc, off, 64);
    __shared__ float wacc[4];
    if ((tid & 63) == 0) wacc[tid >> 6] = acc;
    __syncthreads();
    if (tid == 0) {
        const double s = (double)wacc[0] + (double)wacc[1]
                       + (double)wacc[2] + (double)wacc[3];
        atomicAdd(acc_out, s);
    }
}

__global__ void ncc_finalize(const double* __restrict__ acc,
                             float* __restrict__ out)
{
    const double n = (double)((size_t)DIMB * DIMS * DIMS * DIMS);
    out[0] = (float)(-acc[0] / n);
}

extern "C" void kernel_launch(void* const* d_in, const int* in_sizes, int n_in,
                              void* d_out, int out_size, void* d_ws, size_t ws_size,
                              hipStream_t stream) {
    const float* pred = (const float*)d_in[0];
    const float* targ = (const float*)d_in[1];
    double* acc = (double*)d_ws;

    hipMemsetAsync(d_ws, 0, sizeof(double), stream);

    dim3 block(TX, TY, 1);
    dim3 grid(DIMS / (TX * DPT), DIMS / TY, DIMB * (DIMS / HCHUNK)); // 3 x 12 x 64
    FusedLocalNormalizedCrossCorrelationLoss_37838661877790_kernel
        <<<grid, block, 0, stream>>>(pred, targ, acc);
    ncc_finalize<<<1, 1, 0, stream>>>(acc, (float*)d_out);
}

// Round 11
// 155.221 us; speedup vs baseline: 1.1711x; 1.1711x over previous
//
#include <hip/hip_runtime.h>

#define DIMB 2
#define DIMS 192
#define DPT 4          // d-outputs per thread
#define TX 16          // d-quads per block (64 d per block)
#define TY 16          // w rows per block
#define HCHUNK 6       // output h rows per block
#define ROWF 72        // floats per staged row (d0b-4 .. d0b+67)
#define ARR_F 432      // 6 rows * 72 floats per array in a wave slab
#define SLAB_F 1024    // floats per wave per ring slot (864 used + pad)

#define AS3 __attribute__((address_space(3)))

// Async global->LDS staging: wave-uniform LDS base + lane*16 (m104 contract);
// global source address is per-lane.
#define GLOAD_LDS16(gp, lp) __builtin_amdgcn_global_load_lds( \
    (const __attribute__((address_space(1))) void*)(gp),      \
    (AS3 void*)(lp), 16, 0, 0)

// Counted waits (T4 idiom): keep the younger stage's loads in flight across
// the wait. "memory" clobber pins memory-op order on both sides.
#define WAITV(n) asm volatile("s_waitcnt vmcnt(" #n ")" ::: "memory")
#define LGKM0    asm volatile("s_waitcnt lgkmcnt(0)" ::: "memory")

// OPAQUE LDS reads: inline-asm ds_read so the compiler's waitcnt pass cannot
// see an alias edge from the global_load_lds DMA writes to these reads (it
// otherwise inserts a conservative vmcnt(0) drain before each plane's first
// LDS read, collapsing the software pipeline to depth-0). Ordering is carried
// entirely by the manual WAITV/LGKM0 contract. Rule #18: consumer must sit
// behind lgkmcnt(0) + sched_barrier(0), done at the call sites.
__device__ __forceinline__ float4 ds_read_f4(const float* p) {
    float4 r;
    asm volatile("ds_read_b128 %0, %1" : "=v"(r) : "v"((const AS3 float*)p));
    return r;
}
__device__ __forceinline__ float ds_read_f1(const float* p) {
    float r;
    asm volatile("ds_read_b32 %0, %1" : "=v"(r) : "v"((const AS3 float*)p));
    return r;
}

// DPP lane shifts within 16-lane rows (tx groups): pure VALU, no LDS pipe.
__device__ __forceinline__ float dpp_left(float x) {   // value of tx-1 neighbor
    const int i = __float_as_int(x);
    return __int_as_float(__builtin_amdgcn_update_dpp(i, i, 0x111, 0xf, 0xf, false));
}
__device__ __forceinline__ float dpp_right(float x) {  // value of tx+1 neighbor
    const int i = __float_as_int(x);
    return __int_as_float(__builtin_amdgcn_update_dpp(i, i, 0x101, 0xf, 0xf, false));
}

__device__ __forceinline__ float ncc_row3(const float (&Pm)[5][DPT],
                                          const float (&Pc)[5][DPT],
                                          const float (&Pn)[5][DPT])
{
    const float inv = 1.0f / 27.0f;
    float acc = 0.f;
#pragma unroll
    for (int j = 0; j < DPT; ++j) {
        const float sI  = Pm[0][j] + Pc[0][j] + Pn[0][j];
        const float sJ  = Pm[1][j] + Pc[1][j] + Pn[1][j];
        const float sII = Pm[2][j] + Pc[2][j] + Pn[2][j];
        const float sJJ = Pm[3][j] + Pc[3][j] + Pn[3][j];
        const float sIJ = Pm[4][j] + Pc[4][j] + Pn[4][j];
        const float uI = sI * inv;
        const float uJ = sJ * inv;
        const float cross = sIJ - uI * sJ;
        const float pvar  = sII - uI * sI;
        const float tvar  = sJJ - uJ * sJ;
        acc += (cross * cross) * __builtin_amdgcn_rcpf(tvar * pvar + 1e-5f);
    }
    return acc;
}

__global__ __launch_bounds__(256)
void FusedLocalNormalizedCrossCorrelationLoss_37838661877790_kernel(
    const float* __restrict__ pred, const float* __restrict__ targ,
    double* __restrict__ acc_out)
{
    // Wave-private slabs, 2-slot ring (r4 structure, 65.4 us baseline).
    __shared__ float L[4][2][SLAB_F];    // 32 KB

    const int tx = threadIdx.x, ty = threadIdx.y;
    const int tid = ty * TX + tx;
    const int lane = tid & 63, wv = tid >> 6;
    const int tyw = ty & 3;                      // ty = 4*wv + tyw
    const int d0b = blockIdx.x * (TX * DPT);     // 0, 64, 128
    const int w0  = blockIdx.y * TY;
    const int bz  = blockIdx.z;
    const int b   = bz >> 5;                     // 2 batches
    const int h0  = (bz & 31) * HCHUNK;          // 32 h-chunks

    // ---- per-thread stage precompute (plane-invariant): 4 chunks/wave ----
    int co[4]; const float* ab[4];
#pragma unroll
    for (int c = 0; c < 4; ++c) {
        const int fi = c * 256 + lane * 4;
        const int a  = (fi >= ARR_F) ? 1 : 0;
        int fi2 = fi - a * ARR_F;
        if (fi2 > ARR_F - 4) fi2 = ARR_F - 4;    // pad tail -> safe duplicate
        const int r = fi2 / ROWF, cl = fi2 % ROWF;
        int gd = d0b - 4 + cl;                   // multiple of 4 -> 16B aligned
        gd = gd < 0 ? 0 : (gd > DIMS - 4 ? DIMS - 4 : gd);
        int wr = w0 - 1 + 4 * wv + r;
        wr = wr < 0 ? 0 : (wr > DIMS - 1 ? DIMS - 1 : wr);
        co[c] = wr * DIMS + gd;                  // clamped; garbage masked later
        ab[c] = a ? targ : pred;
    }

    auto stage = [&](int slot, int hh) {
        const int hhc = hh < 0 ? 0 : (hh > DIMS - 1 ? DIMS - 1 : hh);
        const size_t po = ((size_t)b * DIMS + hhc) * (DIMS * DIMS);
        float* lb = &L[wv][slot][0];             // wave-uniform base
#pragma unroll
        for (int c = 0; c < 4; ++c)
            GLOAD_LDS16(ab[c] + po + co[c], lb + c * 256);
    };

    // d-edge masks: window ends refer to gd = d0b-1 / d0b+64, invalid only at
    // the global d boundaries (clamped loads put garbage there).
    const bool lo_mask = (tx == 0)      && (blockIdx.x == 0);
    const bool hi_mask = (tx == TX - 1) && (blockIdx.x == gridDim.x - 1);
    const int rb0 = 4 * tx;

    auto plane = [&](int slot, int hh, float (&P)[5][DPT]) {
#pragma unroll
        for (int c5 = 0; c5 < 5; ++c5)
#pragma unroll
            for (int j = 0; j < DPT; ++j) P[c5][j] = 0.f;
        if (hh < 0 || hh >= DIMS) return;        // uniform per block
        const float* Lp = &L[wv][slot][0];
        const float* Lt = Lp + ARR_F;
#pragma unroll
        for (int dw = 0; dw < 3; ++dw) {
            const int wr = w0 + ty + dw - 1;
            if (wr < 0 || wr >= DIMS) continue;  // garbage halo row (per-ty uniform)
            const int rb = (tyw + dw) * ROWF + rb0;
            // Opaque LDS reads (no compiler alias edge to the DMA writes).
            const float4 pm = ds_read_f4(Lp + rb + 4);
            const float4 tm = ds_read_f4(Lt + rb + 4);
            float pe = 0.f, te = 0.f;
            if (tx == 0)      { pe = ds_read_f1(Lp + rb + 3); te = ds_read_f1(Lt + rb + 3); }
            if (tx == TX - 1) { pe = ds_read_f1(Lp + rb + 8); te = ds_read_f1(Lt + rb + 8); }
            LGKM0;                                   // reads landed
            __builtin_amdgcn_sched_barrier(0);       // rule #18: pin consumers
            // Halo words from neighbor lanes via DPP row shifts.
            float p0 = dpp_left (pm.w);
            float p5 = dpp_right(pm.x);
            float t0 = dpp_left (tm.w);
            float t5 = dpp_right(tm.x);
            if (tx == 0)      { p0 = pe; t0 = te; }
            if (tx == TX - 1) { p5 = pe; t5 = te; }
            if (lo_mask) { p0 = 0.f; t0 = 0.f; }
            if (hi_mask) { p5 = 0.f; t5 = 0.f; }
            const float pv[6] = {p0, pm.x, pm.y, pm.z, pm.w, p5};
            const float tv[6] = {t0, tm.x, tm.y, tm.z, tm.w, t5};
            float pp[6], tt[6], pt[6];
#pragma unroll
            for (int k = 0; k < 6; ++k) {
                pp[k] = pv[k] * pv[k];
                tt[k] = tv[k] * tv[k];
                pt[k] = pv[k] * tv[k];
            }
#define WSUM(dst, a)                                            \
            { const float c12 = a[1] + a[2], c34 = a[3] + a[4]; \
              dst[0] += a[0] + c12; dst[1] += c12 + a[3];       \
              dst[2] += a[2] + c34; dst[3] += c34 + a[5]; }
            WSUM(P[0], pv)
            WSUM(P[1], tv)
            WSUM(P[2], pp)
            WSUM(P[3], tt)
            WSUM(P[4], pt)
#undef WSUM
        }
    };

    // Barrier-free per-wave pipeline (r4 schedule, unchanged). Plane q
    // (hh = h0-1+q) in slot q&1; WAITV(4) = own oldest stage landed while the
    // younger stage's 4 loads stay in flight; LGKM0 then re-stage the slot.
    float PA[5][DPT], PB[5][DPT], PC[5][DPT];
    float acc = 0.f;

    stage(0, h0 - 1);
    stage(1, h0);
    WAITV(4); plane(0, h0 - 1, PA); LGKM0; stage(0, h0 + 1);
    WAITV(4); plane(1, h0,     PB); LGKM0; stage(1, h0 + 2);
    WAITV(4); plane(0, h0 + 1, PC); LGKM0; stage(0, h0 + 3);
    acc += ncc_row3(PA, PB, PC);
    WAITV(4); plane(1, h0 + 2, PA); LGKM0; stage(1, h0 + 4);
    acc += ncc_row3(PB, PC, PA);
    WAITV(4); plane(0, h0 + 3, PB); LGKM0; stage(0, h0 + 5);
    acc += ncc_row3(PC, PA, PB);
    WAITV(4); plane(1, h0 + 4, PC); LGKM0; stage(1, h0 + 6);
    acc += ncc_row3(PA, PB, PC);
    WAITV(4); plane(0, h0 + 5, PA);
    acc += ncc_row3(PB, PC, PA);
    WAITV(0); plane(1, h0 + 6, PB);
    acc += ncc_row3(PC, PA, PB);

    // Reduction: wave shuffle tree -> LDS -> one fp64 atomic per block.
#pragma unroll
    for (int off = 32; off > 0; off >>= 1)
        acc += __shfl_down(acc, off, 64);
    __shared__ float wacc[4];
    if ((tid & 63) == 0) wacc[tid >> 6] = acc;
    __syncthreads();
    if (tid == 0) {
        const double s = (double)wacc[0] + (double)wacc[1]
                       + (double)wacc[2] + (double)wacc[3];
        atomicAdd(acc_out, s);
    }
}

__global__ void ncc_finalize(const double* __restrict__ acc,
                             float* __restrict__ out)
{
    const double n = (double)((size_t)DIMB * DIMS * DIMS * DIMS);
    out[0] = (float)(-acc[0] / n);
}

extern "C" void kernel_launch(void* const* d_in, const int* in_sizes, int n_in,
                              void* d_out, int out_size, void* d_ws, size_t ws_size,
                              hipStream_t stream) {
    const float* pred = (const float*)d_in[0];
    const float* targ = (const float*)d_in[1];
    double* acc = (double*)d_ws;

    hipMemsetAsync(d_ws, 0, sizeof(double), stream);

    dim3 block(TX, TY, 1);
    dim3 grid(DIMS / (TX * DPT), DIMS / TY, DIMB * (DIMS / HCHUNK)); // 3 x 12 x 64
    FusedLocalNormalizedCrossCorrelationLoss_37838661877790_kernel
        <<<grid, block, 0, stream>>>(pred, targ, acc);
    ncc_finalize<<<1, 1, 0, stream>>>(acc, (float*)d_out);
}